// Round 6
// baseline (475.850 us; speedup 1.0000x reference)
//
#include <hip/hip_runtime.h>

// EventTransformer on MI355X. B=2, N=8192, C=CN=64, M=16, H=180, W=240.
// fp32 internal in d_ws. I/O dtype (fp32/bf16) runtime-detected.
//
// R17 (on R16 base = 327.9us, kFPS 83.1):
// (1) kFPS grid.y=4 in par mode: g==3 blocks zero the non-aliased 13.7MB of
//     space DURING the latency-bound rendezvous (kFPS runs at 1% HBM / 3%
//     VALU - chip idle). Post-kFPS kZero shrinks to the 8MB A/C-aliased
//     prefix. Zero region provably disjoint from A/B/C/tail.
// (2) kStat+kOut fused -> kOut2 with in-dispatch arrival barrier (675
//     blocks/batch, 16.6KB LDS -> 8 blocks/CU, all 1350 co-resident; same
//     intra-dispatch trust model as the kFPS rendezvous). Saves one 22MB
//     space read + one dispatch.
// (3) kC: __shfl broadcasts (ds_bpermute) replaced by LDS-staged broadcast
//     ds_read_b128 (sig is replicated across 16-lane groups; lxo is lane=
//     channel data): 80 bpermute/point -> 20 b128 + 2 stores. lred unioned
//     onto LX/SIG to keep LDS at 38.5KB = 4 blocks/CU (unchanged).

typedef unsigned short u16;
typedef unsigned long long ull;

#define NB 8192
#define IMG_H 180
#define IMG_W 240
#define HWPIX (IMG_H*IMG_W)          // 43200
#define SPB (HWPIX*64)               // 2,764,800 floats
#define NC (NB*64)                   // 524,288

// tail-relative offsets (floats), per-batch strides noted
#define TT_AC    0        // +bb*8192
#define TT_T     16384    // +bb*8192
#define TT_W1    32768
#define TT_EDGEV 32960    // +bb*1024
#define TT_EDGEF 35008    // +bb*1024
#define TT_S     37056    // +bb*1024  (holds SW = S@Wsa2)
#define TT_SEL   39104    // +bb*3072
#define TT_CG    45248    // +bb*64
#define TT_ESUM  45376    // +bb*16
#define TT_STATS 45408    // +bb*16
#define TT_SYNC  45440    // +(bb*3+g)*32 ; [par][blk] 2x8 ull
#define TT_GCNT  45632    // +bb*16 ; [0]=FPS gcnt, [8]=kOut2 arrival
#define TT_LXS   45664    // +bb*64 (LXSUM, accumulated by kC atomicAdd)
#define TT_ZOFF  45376
#define TT_ZCNT  416      // covers ESUM..LXS (45376..45791)
#define TT_TOT   45792

__device__ __forceinline__ float bf2f(u16 u){
  union { unsigned int i; float f; } w; w.i = ((unsigned int)u) << 16; return w.f;
}
__device__ __forceinline__ u16 f2bf(float f){
  union { unsigned int i; float f; } w; w.f = f;
  unsigned int x = w.i;
  x += 0x7fffu + ((x >> 16) & 1u);   // RNE
  return (u16)(x >> 16);
}
__device__ __forceinline__ bool isbf(const void* ev){
  unsigned w3 = ((const unsigned*)ev)[3];
  return !(w3 == 0x3F800000u || w3 == 0xBF800000u);
}
__device__ __forceinline__ float ld(const void* p, int i, bool bf){
  return bf ? bf2f(((const u16*)p)[i]) : ((const float*)p)[i];
}
__device__ __forceinline__ void stout(void* o, long i, float v, bool bf){
  if (bf) ((u16*)o)[i] = f2bf(v); else ((float*)o)[i] = v;
}
__device__ __forceinline__ float waveSum(float v){
#pragma unroll
  for (int m = 1; m < 64; m <<= 1) v += __shfl_xor(v, m, 64);
  return v;
}
__device__ __forceinline__ ull waveMaxU64(ull v){
#pragma unroll
  for (int m = 1; m < 64; m <<= 1){
    ull o = (ull)__shfl_xor((long long)v, m, 64);
    if (o > v) v = o;
  }
  return v;
}
// pack: [52:45]=phase, [44:13]=dist bits (d>=0), [12:0]=8191-idx (tie->min idx)
__device__ __forceinline__ ull packPDI(int phase, float d, int n){
  return ((ull)phase << 45) | ((ull)__float_as_uint(d) << 13) | (ull)(8191 - n);
}
__device__ __forceinline__ int unpackI(ull p){ return 8191 - (int)(p & 0x1FFFull); }

// ---- kW: weight precompute + tail zero (runs once)
__global__ void kW(const void* __restrict__ ev, const void* __restrict__ Wq,
                   const void* __restrict__ Wk, const void* __restrict__ Wpe,
                   const void* __restrict__ w1, float* __restrict__ ws, int tail){
  const bool bf = isbf(ev);
  const int tid = threadIdx.x;  // 256
  for (int i = tid; i < TT_ZCNT; i += 256) ws[tail + TT_ZOFF + i] = 0.f;
  if (tid < 64){
    float s1 = 0.f, s2 = 0.f;
    for (int c = 0; c < 64; c++){
      float wc = ld(w1, c, bf);
      s1 += ld(Wq, tid*64 + c, bf) * wc;
      s2 += ld(Wk, tid*64 + c, bf) * wc;
    }
    ws[tail + TT_W1 + tid] = s1;
    ws[tail + TT_W1 + 64 + tid] = s2;
    if (tid < 4){
      float s3 = 0.f;
      for (int c = 0; c < 64; c++) s3 += ld(Wpe, tid*64 + c, bf) * ld(w1, c, bf);
      ws[tail + TT_W1 + 128 + tid] = s3;
    }
  }
}

// ---- kA: 1024 blocks/batch, 8 rows each. Fused ESUM (was kE):
// event scalars are lane-uniform per wave, so lane 0's partial = wave total.
__global__ void __launch_bounds__(256, 4) kA(const void* __restrict__ ev,
    const void* __restrict__ Wm, const void* __restrict__ Wpe,
    const void* __restrict__ Wv, float* __restrict__ ws,
    int offA, int strA, int tail, int bb0){
  const bool bf = isbf(ev);
  const int bb = bb0 + blockIdx.z;
  const int lane = threadIdx.x & 63, w = threadIdx.x >> 6;
  float* A = ws + offA + (size_t)bb*strA;
  const float wq1 = ws[tail + TT_W1 + lane];
  const float wk1 = ws[tail + TT_W1 + 64 + lane];
  const float wp10 = ws[tail+TT_W1+128], wp11 = ws[tail+TT_W1+129],
              wp12 = ws[tail+TT_W1+130], wp13 = ws[tail+TT_W1+131];
  const float wm0 = ld(Wm, 0*64+lane, bf), wm1 = ld(Wm, 1*64+lane, bf),
              wm2 = ld(Wm, 2*64+lane, bf), wm3 = ld(Wm, 3*64+lane, bf);
  const bool edgeBlk = (blockIdx.x == 0 || blockIdx.x == 1023);
  float se0 = 0.f, se1 = 0.f, se2 = 0.f, se3 = 0.f;   // per-wave event sums
#pragma unroll
  for (int i = 0; i < 2; i++){
    const int n = blockIdx.x*8 + w + 4*i;
    const int e4 = (bb*NB + n)*4;
    float e0 = ld(ev, e4+0, bf), e1 = ld(ev, e4+1, bf),
          e2 = ld(ev, e4+2, bf), e3 = ld(ev, e4+3, bf);
    se0 += e0; se1 += e1; se2 += e2; se3 += e3;
    float lx = e0*wm0 + e1*wm1 + e2*wm2 + e3*wm3;
    float epe = e0*wp10 + e1*wp11 + e2*wp12 + e3*wp13;
    float acv = waveSum(lx * wq1) + epe;
    float tv  = waveSum(lx * wk1) + epe;
    A[n*64 + lane] = lx;
    if (lane == 0){
      ws[tail + TT_AC + bb*8192 + n] = acv;
      ws[tail + TT_T  + bb*8192 + n] = tv;
    }
    if (edgeBlk && (n < 8 || n >= NB-8)){
      int e = (n < 8) ? n : (n - (NB-16));
      float v = 0.f;
      for (int cn = 0; cn < 64; cn++)
        v += __shfl(lx, cn, 64) * ld(Wv, cn*64 + lane, bf);
      float f = e0*ld(Wpe, lane, bf) + e1*ld(Wpe, 64+lane, bf)
              + e2*ld(Wpe, 128+lane, bf) + e3*ld(Wpe, 192+lane, bf);
      ws[tail + TT_EDGEV + bb*1024 + e*64 + lane] = v;
      ws[tail + TT_EDGEF + bb*1024 + e*64 + lane] = f;
    }
  }
  __shared__ float esum[4][4];
  if (lane == 0){ esum[w][0]=se0; esum[w][1]=se1; esum[w][2]=se2; esum[w][3]=se3; }
  __syncthreads();
  if (threadIdx.x < 4)
    atomicAdd(&ws[tail + TT_ESUM + bb*16 + threadIdx.x],
              esum[0][threadIdx.x]+esum[1][threadIdx.x]+esum[2][threadIdx.x]+esum[3][threadIdx.x]);
}

// ---- kB: VSUM from ESUM algebra; S[m,c]; SW[m] = S[m]@Wsa2 (hoisted)
__global__ void __launch_bounds__(64) kB(const void* __restrict__ ev,
    const void* __restrict__ Wm, const void* __restrict__ Wv,
    const void* __restrict__ Wsa2, float* __restrict__ ws, int tail, int bb0){
  const bool bf = isbf(ev);
  const int bb = bb0 + blockIdx.z;
  const int m = blockIdx.x, lane = threadIdx.x;
  float tm = 0.f;
#pragma unroll
  for (int i = 0; i < 4; i++) tm += ws[tail + TT_ESUM + bb*16 + i] * ld(Wm, i*64 + lane, bf);
  float vs0 = 0.f, vs1 = 0.f;
#pragma unroll
  for (int j = 0; j < 64; j += 2){
    vs0 += __shfl(tm, j, 64)   * ld(Wv, j*64 + lane, bf);
    vs1 += __shfl(tm, j+1, 64) * ld(Wv, (j+1)*64 + lane, bf);
  }
  float vsum = vs0 + vs1;
  const int d = m - 8;
  float sv = 0.f, sf = 0.f;
  const float* EV = ws + tail + TT_EDGEV + bb*1024;
  const float* EF = ws + tail + TT_EDGEF + bb*1024;
  if (d < 0){
    for (int e = 16 + d; e < 16; e++){ sv += EV[e*64+lane]; sf += EF[e*64+lane]; }
  } else {
    for (int e = 0; e < d; e++){ sv += EV[e*64+lane]; sf += EF[e*64+lane]; }
  }
  float S = vsum - sv + sf;
  float sw0 = 0.f, sw1 = 0.f;
#pragma unroll
  for (int c = 0; c < 64; c += 2){
    sw0 += __shfl(S, c, 64)   * ld(Wsa2, c*64 + lane, bf);
    sw1 += __shfl(S, c+1, 64) * ld(Wsa2, (c+1)*64 + lane, bf);
  }
  ws[tail + TT_S + bb*1024 + m*64 + lane] = sw0 + sw1;
}

// ---- kC: softmax + lx_out + kg/vg. Broadcast operands staged in LDS and
// read via ds_read_b128 (replaces ds_bpermute __shfl). LXSUM via atomicAdd.
__global__ void __launch_bounds__(256) kC(const void* __restrict__ ev,
    const void* __restrict__ gWk, const void* __restrict__ gWv,
    float* __restrict__ ws,
    int offA, int strA, int offB, int strB, int offC, int strC,
    int tail, int bb0){
  const bool bf = isbf(ev);
  const int bb = bb0 + blockIdx.z;
  float* A = ws + offA + (size_t)bb*strA;
  float* Bp = ws + offB + (size_t)bb*strB;
  float* Cp = ws + offC + (size_t)bb*strC;
  __shared__ float SW_lds[1024];
  __shared__ float WK[4096];     // gWk in LDS (16 KB)
  __shared__ float WV[4096];     // gWv in LDS (16 KB)
  __shared__ __align__(16) float LXU[8*64 + 8*16];  // LX[8][64] | SIG[8][16]; reused as lred
  const int tid = threadIdx.x, lane = tid & 63, w = tid >> 6;
  float* LX  = LXU;
  float* SIG = LXU + 512;
  for (int i = tid; i < 1024; i += 256) SW_lds[i] = ws[tail + TT_S + bb*1024 + i];
  for (int i = tid; i < 4096; i += 256){
    WK[i] = ld(gWk, i, bf);
    WV[i] = ld(gWv, i, bf);
  }
  __syncthreads();
  float lxsum = 0.f;
#pragma unroll
  for (int i = 0; i < 2; i++){
    const int p = w + 4*i;
    const int n = blockIdx.x*8 + p;
    float lx  = A[n*64 + lane];
    float acn = ws[tail + TT_AC + bb*8192 + n];
    const int m = lane & 15;
    const int j = n + m - 8;
    float tv = (j >= 0 && j < NB) ? ws[tail + TT_T + bb*8192 + j] : 0.f;
    float logit = acn - tv;
    float mx = logit;
#pragma unroll
    for (int k = 1; k < 16; k <<= 1) mx = fmaxf(mx, __shfl_xor(mx, k, 64));
    float ex = expf(logit - mx);
    float sm = ex;
#pragma unroll
    for (int k = 1; k < 16; k <<= 1) sm += __shfl_xor(sm, k, 64);
    float sig = ex / sm;
    // sig is identical across the four 16-lane groups (depends only on m,n)
    if (lane < 16) SIG[p*16 + lane] = sig;
    float sa = 0.f;
#pragma unroll
    for (int mm = 0; mm < 16; mm += 4){
      float4 s4 = *(const float4*)&SIG[p*16 + mm];   // broadcast b128
      sa += s4.x*SW_lds[ mm   *64+lane] + s4.y*SW_lds[(mm+1)*64+lane]
          + s4.z*SW_lds[(mm+2)*64+lane] + s4.w*SW_lds[(mm+3)*64+lane];
    }
    float lxo = lx + sa;
    LX[p*64 + lane] = lxo;      // lane = channel of point p
    Bp[n*64 + lane] = lxo;
    lxsum += lxo;
  }
  // kg/vg: x broadcast from LDS b128 (same wave wrote LX[p]); weights b32
#pragma unroll
  for (int i = 0; i < 2; i++){
    const int p = w + 4*i;
    const int n = blockIdx.x*8 + p;
    float k0 = 0.f, v0 = 0.f;
#pragma unroll
    for (int cn = 0; cn < 64; cn += 4){
      float4 x4 = *(const float4*)&LX[p*64 + cn];    // broadcast b128
      k0 += x4.x*WK[ cn   *64+lane] + x4.y*WK[(cn+1)*64+lane]
          + x4.z*WK[(cn+2)*64+lane] + x4.w*WK[(cn+3)*64+lane];
      v0 += x4.x*WV[ cn   *64+lane] + x4.y*WV[(cn+1)*64+lane]
          + x4.z*WV[(cn+2)*64+lane] + x4.w*WV[(cn+3)*64+lane];
    }
    A[n*64 + lane] = k0;
    Cp[n*64 + lane] = v0;
  }
  __syncthreads();               // all waves done with LXU -> reuse as lred
  float* lred = LXU;
  lred[w*64 + lane] = lxsum;
  __syncthreads();
  if (tid < 64)
    atomicAdd(&ws[tail + TT_LXS + bb*64 + tid],
              lred[tid]+lred[64+tid]+lred[128+tid]+lred[192+tid]);
}

// ---- kFPS: grid (8, par?4:3, nb) x 512 thr. R11 rendezvous (proven).
// g==3 blocks (par only): zero non-aliased space during the rendezvous.
__global__ void __launch_bounds__(512) kFPS(const void* __restrict__ ev,
    const void* __restrict__ gWk, const void* __restrict__ gWv,
    const void* __restrict__ gWpe, const void* __restrict__ gWsa1,
    const void* __restrict__ gWsa2, float* __restrict__ ws,
    int offA, int strA, int offB, int strB, int offC, int strC,
    int offSp, int strSp, int tail, int bb0){
  const int g = blockIdx.y, idx = blockIdx.x;
  const int bb = bb0 + blockIdx.z;
  const int tid = threadIdx.x, lane = tid & 63, w = tid >> 6;

  if (g == 3){
    // par-mode only. Zero this batch's space minus the A/C-aliased prefix.
    // bb=0 space = [offSp, offSp+SPB); aliased prefix = [offSp, offSp+4NC).
    // bb=1 space = [offSp+SPB, offSp+2SPB); fully non-aliased.
    float4 z = make_float4(0.f, 0.f, 0.f, 0.f);
    size_t base; unsigned cnt4;
    if (blockIdx.z == 0){ base = (size_t)offSp + 4u*NC; cnt4 = (SPB - 4*NC)/4; }
    else                { base = (size_t)offSp + (size_t)strSp; cnt4 = SPB/4; }
    float4* p = (float4*)(ws + base);
    for (unsigned i = idx*512u + tid; i < cnt4; i += 8u*512u) p[i] = z;
    return;
  }

  const float* pts = ws + (g == 0 ? offB + (size_t)bb*strB
                         : g == 1 ? offA + (size_t)bb*strA
                                  : offC + (size_t)bb*strC);
  ull* slot = (ull*)(ws + tail + TT_SYNC + (bb*3 + g)*32);  // [par][blk] 2x8 ull
  int* gcnt = (int*)(ws + tail + TT_GCNT + bb*16);

  __shared__ float cent[64];
  __shared__ float lxsS[64];
  __shared__ ull   wvS[8];
  __shared__ int   selS[16];
  __shared__ int   sCur;
  __shared__ float gfS[1024];
  __shared__ float betaS[16];
  __shared__ float GS[64];

  const int n0 = idx*1024 + tid;       // +0 and +512
  float4 P[2][16];
#pragma unroll
  for (int j = 0; j < 2; j++)
#pragma unroll
    for (int i = 0; i < 16; i++)
      P[j][i] = ((const float4*)(pts + (size_t)(n0 + j*512)*64))[i];

  const bool bf = isbf(ev);
  // head: LXSUM accumulated by kC; cent analytically per group
  if (tid < 64){
    float lxs = ws[tail + TT_LXS + bb*64 + tid];
    lxsS[tid] = lxs;
    float c;
    if (g == 0) c = lxs * (1.0f/NB);
    else {
      const void* W = (g == 1) ? gWk : gWv;
      float s = 0.f;
#pragma unroll
      for (int j = 0; j < 64; j++) s += __shfl(lxs, j, 64) * ld(W, j*64 + tid, bf);
      c = s * (1.0f/NB);
    }
    cent[tid] = c;
  }
  __syncthreads();

  const float4* cv = (const float4*)cent;
  float md[2] = {1e10f, 1e10f};
  int cur;

  // phase 1: farthest0 (dist to bary, no md update)
  {
    float dd[2];
#pragma unroll
    for (int j = 0; j < 2; j++){
      float d = 0.f;
#pragma unroll
      for (int i = 0; i < 16; i++){
        float4 c = cv[i];
        float dx = P[j][i].x-c.x, dy = P[j][i].y-c.y, dz = P[j][i].z-c.z, dw = P[j][i].w-c.w;
        d += dx*dx; d += dy*dy; d += dz*dz; d += dw*dw;
      }
      dd[j] = d;
    }
    ull p0 = packPDI(1, dd[0], n0);
    ull p1 = packPDI(1, dd[1], n0 + 512);
    ull bp = waveMaxU64(p0 > p1 ? p0 : p1);
    if (lane == 0) wvS[w] = bp;
    __syncthreads();
    if (w == 0){
      ull v = (lane < 8) ? wvS[lane] : 0;
#pragma unroll
      for (int m = 1; m < 8; m <<= 1){
        ull o = (ull)__shfl_xor((long long)v, m, 64);
        if (o > v) v = o;
      }
      if (lane == 0)
        __hip_atomic_store(&slot[8 + idx], v, __ATOMIC_RELEASE, __HIP_MEMORY_SCOPE_AGENT);
      ull got;
      for (;;){
        got = (lane < 8) ? __hip_atomic_load(&slot[8 + lane], __ATOMIC_RELAXED, __HIP_MEMORY_SCOPE_AGENT) : 0;
        ull ok = __ballot(lane >= 8 || (int)(got >> 45) == 1);
        if (ok == ~0ull) break;
        __builtin_amdgcn_s_sleep(1);
      }
#pragma unroll
      for (int m = 1; m < 8; m <<= 1){
        ull o = (ull)__shfl_xor((long long)got, m, 64);
        if (o > got) got = o;
      }
      if (lane == 0) sCur = unpackI(got);
    }
    __syncthreads();
    cur = sCur;
  }

  for (int it = 0; ; it++){
    if (tid == 0) selS[it] = cur;
    if (it == 15) break;
    if (tid < 16) ((float4*)cent)[tid] = ((const float4*)(pts + (size_t)cur*64))[tid];
    __syncthreads();
    const int phase = it + 2;
    float dd[2];
#pragma unroll
    for (int j = 0; j < 2; j++){
      float d = 0.f;
#pragma unroll
      for (int i = 0; i < 16; i++){
        float4 c = cv[i];
        float dx = P[j][i].x-c.x, dy = P[j][i].y-c.y, dz = P[j][i].z-c.z, dw = P[j][i].w-c.w;
        d += dx*dx; d += dy*dy; d += dz*dz; d += dw*dw;
      }
      md[j] = fminf(md[j], d);
      dd[j] = md[j];
    }
    ull p0 = packPDI(phase, dd[0], n0);
    ull p1 = packPDI(phase, dd[1], n0 + 512);
    ull bp = waveMaxU64(p0 > p1 ? p0 : p1);
    if (lane == 0) wvS[w] = bp;
    __syncthreads();
    const int par = phase & 1;
    if (w == 0){
      ull v = (lane < 8) ? wvS[lane] : 0;
#pragma unroll
      for (int m = 1; m < 8; m <<= 1){
        ull o = (ull)__shfl_xor((long long)v, m, 64);
        if (o > v) v = o;
      }
      if (lane == 0)
        __hip_atomic_store(&slot[par*8 + idx], v, __ATOMIC_RELEASE, __HIP_MEMORY_SCOPE_AGENT);
      ull got;
      for (;;){
        got = (lane < 8) ? __hip_atomic_load(&slot[par*8 + lane], __ATOMIC_RELAXED, __HIP_MEMORY_SCOPE_AGENT) : 0;
        ull ok = __ballot(lane >= 8 || (int)(got >> 45) == phase);
        if (ok == ~0ull) break;
        __builtin_amdgcn_s_sleep(1);
      }
#pragma unroll
      for (int m = 1; m < 8; m <<= 1){
        ull o = (ull)__shfl_xor((long long)got, m, 64);
        if (o > got) got = o;
      }
      if (lane == 0) sCur = unpackI(got);
    }
    __syncthreads();
    cur = sCur;
  }
  __syncthreads();

  if (idx == 0){
    if (tid == 0){
      for (int i = 1; i < 16; i++){
        int key = selS[i]; int j = i - 1;
        while (j >= 0 && selS[j] > key){ selS[j+1] = selS[j]; j--; }
        selS[j+1] = key;
      }
    }
    __syncthreads();
    for (int idx2 = tid; idx2 < 1024; idx2 += 512)
      ws[tail + TT_SEL + bb*3072 + g*1024 + idx2] = pts[(size_t)selS[idx2 >> 6]*64 + (idx2 & 63)];
    __threadfence();
  }
  __syncthreads();
  if (tid == 0) atomicAdd(gcnt, 1);
  if (g != 0 || idx != 0) return;

  // ---- kG tail (per batch); wpec register-resident (P dead here)
  if (tid == 0){
    while (__hip_atomic_load(gcnt, __ATOMIC_RELAXED, __HIP_MEMORY_SCOPE_AGENT) < 24)
      __builtin_amdgcn_s_sleep(1);
    __threadfence();
  }
  __syncthreads();
  if (tid < 64){
    const float gw1 = ld(gWsa1, tid, bf);
    float wpec[64];
#pragma unroll
    for (int cn = 0; cn < 64; cn++) wpec[cn] = ld(gWpe, cn*64 + tid, bf);
    float lxs = lxsS[tid];
    float G = 0.f;
#pragma unroll
    for (int cn = 0; cn < 64; cn++) G += __shfl(lxs, cn, 64) * wpec[cn];
    GS[tid] = G;
    const float* selp = ws + tail + TT_SEL + bb*3072;
    for (int m = 0; m < 16; m++){
      float plx = selp[m*64 + tid];
      float g2 = 0.f;
#pragma unroll
      for (int cn = 0; cn < 64; cn++) g2 += __shfl(plx, cn, 64) * wpec[cn];
      gfS[m*64 + tid] = g2;
      float pkv = selp[1024 + m*64 + tid];
      float part = waveSum((pkv + g2) * gw1);
      if (tid == 0) betaS[m] = part;
    }
  }
  __syncthreads();
  if (tid < 64){
    float mx = -1e30f;
    for (int m = 0; m < 16; m++) mx = fmaxf(mx, -betaS[m]);
    float ssum = 0.f;
    for (int m = 0; m < 16; m++) ssum += expf(-betaS[m] - mx);
    float A = 0.f;
    for (int m = 0; m < 16; m++){
      float sg = expf(-betaS[m] - mx) / ssum;
      float pv = ws[tail + TT_SEL + bb*3072 + 2048 + m*64 + tid];
      float Sg = 8192.0f * (pv - gfS[m*64 + tid]) + GS[tid];
      A += sg * Sg;
    }
    float cg = 0.f;
#pragma unroll
    for (int cn = 0; cn < 64; cn++) cg += __shfl(A, cn, 64) * ld(gWsa2, cn*64 + tid, bf);
    ws[tail + TT_CG + bb*64 + tid] = cg;
  }
}

// ---- kZero: zero [base, base+count4*4) floats (float4 stores)
__global__ void kZero(float* __restrict__ ws, int base, unsigned count4){
  unsigned i = blockIdx.x*256u + threadIdx.x;
  if (i < count4)
    ((float4*)(ws + base))[i] = make_float4(0.f, 0.f, 0.f, 0.f);
}

// ---- kImg: LN + GELU + scatter-add
__global__ void __launch_bounds__(256, 4) kImg(const void* __restrict__ ev,
    const void* __restrict__ lnw, const void* __restrict__ lnb,
    float* __restrict__ ws, int offB, int strB, int offSp, int strSp,
    int tail, int bb0){
  const bool bf = isbf(ev);
  const int bb = bb0 + blockIdx.z;
  const int lane = threadIdx.x & 63, w = threadIdx.x >> 6;
  const float cg = ws[tail + TT_CG + bb*64 + lane];
  const float lw = ld(lnw, lane, bf), lb = ld(lnb, lane, bf);
  float* space = ws + offSp + (size_t)bb*strSp;
  const float* Bp = ws + offB + (size_t)bb*strB;
#pragma unroll
  for (int i = 0; i < 2; i++){
    const int n = blockIdx.x*8 + w + 4*i;
    float x = Bp[n*64 + lane] + cg;
    float mu = waveSum(x) * (1.0f/64.0f);
    float dv = x - mu;
    float var = waveSum(dv*dv) * (1.0f/64.0f);
    float xn = dv / sqrtf(var + 1e-5f);
    float y = xn * lw + lb;
    float h = 0.5f * y * (1.0f + erff(y * 0.70710678118654752f));
    const int e4 = (bb*NB + n)*4;
    float exf = ld(ev, e4+0, bf), eyf = ld(ev, e4+1, bf), epf = ld(ev, e4+3, bf);
    int xi = (int)floorf(exf), yi = (int)floorf(eyf);
    int flat = yi*IMG_W + xi;
    flat = max(0, min(HWPIX-1, flat));
    atomicAdd(space + flat*64 + lane, epf * h);
  }
}

// ---- kOut2: fused kStat+kOut. Phase A: load tile + partial stats + atomic.
// Arrival barrier (all 675 blocks/batch co-resident). Phase B: normalize+out.
__global__ void __launch_bounds__(256) kOut2(const void* __restrict__ ev,
    float* __restrict__ ws, void* __restrict__ out,
    int offSp, int strSp, int tail, int bb0, int nArrive){
  const bool bf = isbf(ev);
  const int bb = bb0 + blockIdx.z;
  __shared__ float tile[64*65];
  __shared__ float rc[4], rs[4], rq[4];
  __shared__ float sStats[3];
  const int tid = threadIdx.x, lane = tid & 63, w = tid >> 6;
  const int hw0 = blockIdx.x*64;
  const float* sp = ws + offSp + (size_t)bb*strSp;
  float cnt = 0.f, sum = 0.f, ssq = 0.f;
#pragma unroll
  for (int i = 0; i < 16; i++){
    int idx = tid + 256*i;
    float x = sp[(size_t)hw0*64 + idx];
    tile[(idx >> 6)*65 + (idx & 63)] = x;
    if (x != 0.f){ cnt += 1.f; sum += x; ssq += x*x; }
  }
  cnt = waveSum(cnt); sum = waveSum(sum); ssq = waveSum(ssq);
  if (lane == 0){ rc[w] = cnt; rs[w] = sum; rq[w] = ssq; }
  __syncthreads();
  float* ST = ws + tail + TT_STATS + bb*16;
  int* cntr = (int*)(ws + tail + TT_GCNT + bb*16 + 8);
  if (tid == 0){
    atomicAdd(&ST[0], rc[0]+rc[1]+rc[2]+rc[3]);
    atomicAdd(&ST[1], rs[0]+rs[1]+rs[2]+rs[3]);
    atomicAdd(&ST[2], rq[0]+rq[1]+rq[2]+rq[3]);
    __threadfence();
    atomicAdd(cntr, 1);
    while (__hip_atomic_load(cntr, __ATOMIC_RELAXED, __HIP_MEMORY_SCOPE_AGENT) < nArrive)
      __builtin_amdgcn_s_sleep(2);
    __threadfence();
    sStats[0] = __hip_atomic_load(&ST[0], __ATOMIC_RELAXED, __HIP_MEMORY_SCOPE_AGENT);
    sStats[1] = __hip_atomic_load(&ST[1], __ATOMIC_RELAXED, __HIP_MEMORY_SCOPE_AGENT);
    sStats[2] = __hip_atomic_load(&ST[2], __ATOMIC_RELAXED, __HIP_MEMORY_SCOPE_AGENT);
  }
  __syncthreads();
  const float cntf = sStats[0];
  const float sumf = sStats[1];
  const float ssqf = sStats[2];
  const float mean = sumf / fmaxf(cntf, 1.f);
  const float m2   = fmaxf(ssqf - sumf*mean, 0.f);
  const float var  = m2 / fmaxf(cntf - 1.f, 1.f);
  const float stdv = sqrtf(var);
  const int c = tid >> 2, sub = tid & 3;
#pragma unroll
  for (int j = 0; j < 16; j++){
    int hwl = sub*16 + j;
    float x = tile[hwl*65 + c];
    float centered = (x != 0.f) ? (x - mean) : x;
    float normed = (stdv > 0.f) ? (centered / stdv) : centered;
    float o = (cntf > 0.f) ? normed : x;
    stout(out, (long)(bb*64 + c)*HWPIX + hw0 + hwl, o, bf);
  }
}

extern "C" void kernel_launch(void* const* d_in, const int* in_sizes, int n_in,
                              void* d_out, int out_size, void* d_ws, size_t ws_size,
                              hipStream_t stream){
  (void)in_sizes; (void)n_in; (void)out_size;
  const void* ev     = d_in[0];
  const void* Wm     = d_in[1];
  const void* Wpe    = d_in[2];
  const void* lnw    = d_in[3];
  const void* lnb    = d_in[4];
  const void* lxWq   = d_in[5];
  const void* lxWk   = d_in[6];
  const void* lxWv   = d_in[7];
  const void* lxWsa1 = d_in[8];
  const void* lxWsa2 = d_in[9];
  // d_in[10] = gx_Wq : unused (cancels in n-independent softmax)
  const void* gxWk   = d_in[11];
  const void* gxWv   = d_in[12];
  const void* gxWpe  = d_in[13];
  const void* gxWsa1 = d_in[14];
  const void* gxWsa2 = d_in[15];
  float* ws = (float*)d_ws;

  // Parallel layout: B[2NC] | SPACE[2SPB] (aliases A,C) | tail
  const int P_TAIL = 2*NC + 2*SPB;
  const size_t PAR_BYTES = (size_t)(P_TAIL + TT_TOT) * 4;
  const bool par = ws_size >= PAR_BYTES;

  int offB, strB, offSp, strSp, offA, strA, offC, strC, tail;
  if (par){
    offB = 0;        strB = NC;
    offSp = 2*NC;    strSp = SPB;
    offA = 2*NC;     strA = NC;
    offC = 4*NC;     strC = NC;
    tail = P_TAIL;
  } else {
    offSp = 0;       strSp = 0;
    offA = 0;        strA = 0;
    offC = NC;       strC = 0;
    offB = SPB;      strB = 0;
    tail = SPB + NC;
  }
  const int nb = par ? 2 : 1;
  const int iters = par ? 1 : 2;

  kW<<<1, 256, 0, stream>>>(ev, lxWq, lxWk, Wpe, lxWsa1, ws, tail);
  for (int t = 0; t < iters; t++){
    const int bb0 = par ? 0 : t;
    kA<<<dim3(1024,1,nb), 256, 0, stream>>>(ev, Wm, Wpe, lxWv, ws, offA, strA, tail, bb0);
    kB<<<dim3(16,1,nb), 64, 0, stream>>>(ev, Wm, lxWv, lxWsa2, ws, tail, bb0);
    kC<<<dim3(1024,1,nb), 256, 0, stream>>>(ev, gxWk, gxWv, ws,
        offA, strA, offB, strB, offC, strC, tail, bb0);
    kFPS<<<dim3(8, par ? 4 : 3, nb), 512, 0, stream>>>(ev, gxWk, gxWv, gxWpe, gxWsa1, gxWsa2, ws,
        offA, strA, offB, strB, offC, strC, offSp, strSp, tail, bb0);
    if (par)
      kZero<<<dim3(2048,1,1), 256, 0, stream>>>(ws, offSp, (unsigned)NC);        // 8MB aliased prefix
    else
      kZero<<<dim3(2700,1,1), 256, 0, stream>>>(ws, offSp, (unsigned)(SPB/4));   // full space
    kImg<<<dim3(1024,1,nb), 256, 0, stream>>>(ev, lnw, lnb, ws, offB, strB, offSp, strSp, tail, bb0);
    kOut2<<<dim3(675,1,nb), 256, 0, stream>>>(ev, ws, d_out, offSp, strSp, tail, bb0, 675);
  }
}

// Round 7
// 325.653 us; speedup vs baseline: 1.4612x; 1.4612x over previous
//
#include <hip/hip_runtime.h>

// EventTransformer on MI355X. B=2, N=8192, C=CN=64, M=16, H=180, W=240.
// fp32 internal in d_ws. I/O dtype (fp32/bf16) runtime-detected.
//
// R18: revert kOut2 (R17's fused kStat+kOut with 1350-block agent-scope
// arrival barrier: 200us/dispatch, WRITE 50MB = LLC spin thrash, 3rd
// repeat of the R13/R14 pathology. RULE: agent-scope spins only with <=8
// pollers/line). kStat + kOut restored byte-identical to R16 (proven:
// stride-65 kOut = 0 bank conflicts). KEPT from R17: (1) kFPS g==3 blocks
// zero non-aliased 13.7MB space during the latency-bound rendezvous +
// shrunken kZero (8MB aliased prefix only); (2) kC LDS-b128 broadcast
// (replaces ds_bpermute). This round's kFPS counters isolate both.

typedef unsigned short u16;
typedef unsigned long long ull;

#define NB 8192
#define IMG_H 180
#define IMG_W 240
#define HWPIX (IMG_H*IMG_W)          // 43200
#define SPB (HWPIX*64)               // 2,764,800 floats
#define NC (NB*64)                   // 524,288

// tail-relative offsets (floats), per-batch strides noted
#define TT_AC    0        // +bb*8192
#define TT_T     16384    // +bb*8192
#define TT_W1    32768
#define TT_EDGEV 32960    // +bb*1024
#define TT_EDGEF 35008    // +bb*1024
#define TT_S     37056    // +bb*1024  (holds SW = S@Wsa2)
#define TT_SEL   39104    // +bb*3072
#define TT_CG    45248    // +bb*64
#define TT_ESUM  45376    // +bb*16
#define TT_STATS 45408    // +bb*16
#define TT_SYNC  45440    // +(bb*3+g)*32 ; [par][blk] 2x8 ull
#define TT_GCNT  45632    // +bb*16
#define TT_LXS   45664    // +bb*64 (LXSUM, accumulated by kC atomicAdd)
#define TT_ZOFF  45376
#define TT_ZCNT  416      // covers ESUM..LXS (45376..45791)
#define TT_TOT   45792

__device__ __forceinline__ float bf2f(u16 u){
  union { unsigned int i; float f; } w; w.i = ((unsigned int)u) << 16; return w.f;
}
__device__ __forceinline__ u16 f2bf(float f){
  union { unsigned int i; float f; } w; w.f = f;
  unsigned int x = w.i;
  x += 0x7fffu + ((x >> 16) & 1u);   // RNE
  return (u16)(x >> 16);
}
__device__ __forceinline__ bool isbf(const void* ev){
  unsigned w3 = ((const unsigned*)ev)[3];
  return !(w3 == 0x3F800000u || w3 == 0xBF800000u);
}
__device__ __forceinline__ float ld(const void* p, int i, bool bf){
  return bf ? bf2f(((const u16*)p)[i]) : ((const float*)p)[i];
}
__device__ __forceinline__ void stout(void* o, long i, float v, bool bf){
  if (bf) ((u16*)o)[i] = f2bf(v); else ((float*)o)[i] = v;
}
__device__ __forceinline__ float waveSum(float v){
#pragma unroll
  for (int m = 1; m < 64; m <<= 1) v += __shfl_xor(v, m, 64);
  return v;
}
__device__ __forceinline__ ull waveMaxU64(ull v){
#pragma unroll
  for (int m = 1; m < 64; m <<= 1){
    ull o = (ull)__shfl_xor((long long)v, m, 64);
    if (o > v) v = o;
  }
  return v;
}
// pack: [52:45]=phase, [44:13]=dist bits (d>=0), [12:0]=8191-idx (tie->min idx)
__device__ __forceinline__ ull packPDI(int phase, float d, int n){
  return ((ull)phase << 45) | ((ull)__float_as_uint(d) << 13) | (ull)(8191 - n);
}
__device__ __forceinline__ int unpackI(ull p){ return 8191 - (int)(p & 0x1FFFull); }

// ---- kW: weight precompute + tail zero (runs once)
__global__ void kW(const void* __restrict__ ev, const void* __restrict__ Wq,
                   const void* __restrict__ Wk, const void* __restrict__ Wpe,
                   const void* __restrict__ w1, float* __restrict__ ws, int tail){
  const bool bf = isbf(ev);
  const int tid = threadIdx.x;  // 256
  for (int i = tid; i < TT_ZCNT; i += 256) ws[tail + TT_ZOFF + i] = 0.f;
  if (tid < 64){
    float s1 = 0.f, s2 = 0.f;
    for (int c = 0; c < 64; c++){
      float wc = ld(w1, c, bf);
      s1 += ld(Wq, tid*64 + c, bf) * wc;
      s2 += ld(Wk, tid*64 + c, bf) * wc;
    }
    ws[tail + TT_W1 + tid] = s1;
    ws[tail + TT_W1 + 64 + tid] = s2;
    if (tid < 4){
      float s3 = 0.f;
      for (int c = 0; c < 64; c++) s3 += ld(Wpe, tid*64 + c, bf) * ld(w1, c, bf);
      ws[tail + TT_W1 + 128 + tid] = s3;
    }
  }
}

// ---- kA: 1024 blocks/batch, 8 rows each. Fused ESUM (was kE):
// event scalars are lane-uniform per wave, so lane 0's partial = wave total.
__global__ void __launch_bounds__(256, 4) kA(const void* __restrict__ ev,
    const void* __restrict__ Wm, const void* __restrict__ Wpe,
    const void* __restrict__ Wv, float* __restrict__ ws,
    int offA, int strA, int tail, int bb0){
  const bool bf = isbf(ev);
  const int bb = bb0 + blockIdx.z;
  const int lane = threadIdx.x & 63, w = threadIdx.x >> 6;
  float* A = ws + offA + (size_t)bb*strA;
  const float wq1 = ws[tail + TT_W1 + lane];
  const float wk1 = ws[tail + TT_W1 + 64 + lane];
  const float wp10 = ws[tail+TT_W1+128], wp11 = ws[tail+TT_W1+129],
              wp12 = ws[tail+TT_W1+130], wp13 = ws[tail+TT_W1+131];
  const float wm0 = ld(Wm, 0*64+lane, bf), wm1 = ld(Wm, 1*64+lane, bf),
              wm2 = ld(Wm, 2*64+lane, bf), wm3 = ld(Wm, 3*64+lane, bf);
  const bool edgeBlk = (blockIdx.x == 0 || blockIdx.x == 1023);
  float se0 = 0.f, se1 = 0.f, se2 = 0.f, se3 = 0.f;   // per-wave event sums
#pragma unroll
  for (int i = 0; i < 2; i++){
    const int n = blockIdx.x*8 + w + 4*i;
    const int e4 = (bb*NB + n)*4;
    float e0 = ld(ev, e4+0, bf), e1 = ld(ev, e4+1, bf),
          e2 = ld(ev, e4+2, bf), e3 = ld(ev, e4+3, bf);
    se0 += e0; se1 += e1; se2 += e2; se3 += e3;
    float lx = e0*wm0 + e1*wm1 + e2*wm2 + e3*wm3;
    float epe = e0*wp10 + e1*wp11 + e2*wp12 + e3*wp13;
    float acv = waveSum(lx * wq1) + epe;
    float tv  = waveSum(lx * wk1) + epe;
    A[n*64 + lane] = lx;
    if (lane == 0){
      ws[tail + TT_AC + bb*8192 + n] = acv;
      ws[tail + TT_T  + bb*8192 + n] = tv;
    }
    if (edgeBlk && (n < 8 || n >= NB-8)){
      int e = (n < 8) ? n : (n - (NB-16));
      float v = 0.f;
      for (int cn = 0; cn < 64; cn++)
        v += __shfl(lx, cn, 64) * ld(Wv, cn*64 + lane, bf);
      float f = e0*ld(Wpe, lane, bf) + e1*ld(Wpe, 64+lane, bf)
              + e2*ld(Wpe, 128+lane, bf) + e3*ld(Wpe, 192+lane, bf);
      ws[tail + TT_EDGEV + bb*1024 + e*64 + lane] = v;
      ws[tail + TT_EDGEF + bb*1024 + e*64 + lane] = f;
    }
  }
  __shared__ float esum[4][4];
  if (lane == 0){ esum[w][0]=se0; esum[w][1]=se1; esum[w][2]=se2; esum[w][3]=se3; }
  __syncthreads();
  if (threadIdx.x < 4)
    atomicAdd(&ws[tail + TT_ESUM + bb*16 + threadIdx.x],
              esum[0][threadIdx.x]+esum[1][threadIdx.x]+esum[2][threadIdx.x]+esum[3][threadIdx.x]);
}

// ---- kB: VSUM from ESUM algebra; S[m,c]; SW[m] = S[m]@Wsa2 (hoisted)
__global__ void __launch_bounds__(64) kB(const void* __restrict__ ev,
    const void* __restrict__ Wm, const void* __restrict__ Wv,
    const void* __restrict__ Wsa2, float* __restrict__ ws, int tail, int bb0){
  const bool bf = isbf(ev);
  const int bb = bb0 + blockIdx.z;
  const int m = blockIdx.x, lane = threadIdx.x;
  float tm = 0.f;
#pragma unroll
  for (int i = 0; i < 4; i++) tm += ws[tail + TT_ESUM + bb*16 + i] * ld(Wm, i*64 + lane, bf);
  float vs0 = 0.f, vs1 = 0.f;
#pragma unroll
  for (int j = 0; j < 64; j += 2){
    vs0 += __shfl(tm, j, 64)   * ld(Wv, j*64 + lane, bf);
    vs1 += __shfl(tm, j+1, 64) * ld(Wv, (j+1)*64 + lane, bf);
  }
  float vsum = vs0 + vs1;
  const int d = m - 8;
  float sv = 0.f, sf = 0.f;
  const float* EV = ws + tail + TT_EDGEV + bb*1024;
  const float* EF = ws + tail + TT_EDGEF + bb*1024;
  if (d < 0){
    for (int e = 16 + d; e < 16; e++){ sv += EV[e*64+lane]; sf += EF[e*64+lane]; }
  } else {
    for (int e = 0; e < d; e++){ sv += EV[e*64+lane]; sf += EF[e*64+lane]; }
  }
  float S = vsum - sv + sf;
  float sw0 = 0.f, sw1 = 0.f;
#pragma unroll
  for (int c = 0; c < 64; c += 2){
    sw0 += __shfl(S, c, 64)   * ld(Wsa2, c*64 + lane, bf);
    sw1 += __shfl(S, c+1, 64) * ld(Wsa2, (c+1)*64 + lane, bf);
  }
  ws[tail + TT_S + bb*1024 + m*64 + lane] = sw0 + sw1;
}

// ---- kC: softmax + lx_out + kg/vg. Broadcast operands staged in LDS and
// read via ds_read_b128 (replaces ds_bpermute __shfl). LXSUM via atomicAdd.
__global__ void __launch_bounds__(256) kC(const void* __restrict__ ev,
    const void* __restrict__ gWk, const void* __restrict__ gWv,
    float* __restrict__ ws,
    int offA, int strA, int offB, int strB, int offC, int strC,
    int tail, int bb0){
  const bool bf = isbf(ev);
  const int bb = bb0 + blockIdx.z;
  float* A = ws + offA + (size_t)bb*strA;
  float* Bp = ws + offB + (size_t)bb*strB;
  float* Cp = ws + offC + (size_t)bb*strC;
  __shared__ float SW_lds[1024];
  __shared__ float WK[4096];     // gWk in LDS (16 KB)
  __shared__ float WV[4096];     // gWv in LDS (16 KB)
  __shared__ __align__(16) float LXU[8*64 + 8*16];  // LX[8][64] | SIG[8][16]; reused as lred
  const int tid = threadIdx.x, lane = tid & 63, w = tid >> 6;
  float* LX  = LXU;
  float* SIG = LXU + 512;
  for (int i = tid; i < 1024; i += 256) SW_lds[i] = ws[tail + TT_S + bb*1024 + i];
  for (int i = tid; i < 4096; i += 256){
    WK[i] = ld(gWk, i, bf);
    WV[i] = ld(gWv, i, bf);
  }
  __syncthreads();
  float lxsum = 0.f;
#pragma unroll
  for (int i = 0; i < 2; i++){
    const int p = w + 4*i;
    const int n = blockIdx.x*8 + p;
    float lx  = A[n*64 + lane];
    float acn = ws[tail + TT_AC + bb*8192 + n];
    const int m = lane & 15;
    const int j = n + m - 8;
    float tv = (j >= 0 && j < NB) ? ws[tail + TT_T + bb*8192 + j] : 0.f;
    float logit = acn - tv;
    float mx = logit;
#pragma unroll
    for (int k = 1; k < 16; k <<= 1) mx = fmaxf(mx, __shfl_xor(mx, k, 64));
    float ex = expf(logit - mx);
    float sm = ex;
#pragma unroll
    for (int k = 1; k < 16; k <<= 1) sm += __shfl_xor(sm, k, 64);
    float sig = ex / sm;
    // sig is identical across the four 16-lane groups (depends only on m,n)
    if (lane < 16) SIG[p*16 + lane] = sig;
    float sa = 0.f;
#pragma unroll
    for (int mm = 0; mm < 16; mm += 4){
      float4 s4 = *(const float4*)&SIG[p*16 + mm];   // broadcast b128
      sa += s4.x*SW_lds[ mm   *64+lane] + s4.y*SW_lds[(mm+1)*64+lane]
          + s4.z*SW_lds[(mm+2)*64+lane] + s4.w*SW_lds[(mm+3)*64+lane];
    }
    float lxo = lx + sa;
    LX[p*64 + lane] = lxo;      // lane = channel of point p
    Bp[n*64 + lane] = lxo;
    lxsum += lxo;
  }
  // kg/vg: x broadcast from LDS b128 (same wave wrote LX[p]); weights b32
#pragma unroll
  for (int i = 0; i < 2; i++){
    const int p = w + 4*i;
    const int n = blockIdx.x*8 + p;
    float k0 = 0.f, v0 = 0.f;
#pragma unroll
    for (int cn = 0; cn < 64; cn += 4){
      float4 x4 = *(const float4*)&LX[p*64 + cn];    // broadcast b128
      k0 += x4.x*WK[ cn   *64+lane] + x4.y*WK[(cn+1)*64+lane]
          + x4.z*WK[(cn+2)*64+lane] + x4.w*WK[(cn+3)*64+lane];
      v0 += x4.x*WV[ cn   *64+lane] + x4.y*WV[(cn+1)*64+lane]
          + x4.z*WV[(cn+2)*64+lane] + x4.w*WV[(cn+3)*64+lane];
    }
    A[n*64 + lane] = k0;
    Cp[n*64 + lane] = v0;
  }
  __syncthreads();               // all waves done with LXU -> reuse as lred
  float* lred = LXU;
  lred[w*64 + lane] = lxsum;
  __syncthreads();
  if (tid < 64)
    atomicAdd(&ws[tail + TT_LXS + bb*64 + tid],
              lred[tid]+lred[64+tid]+lred[128+tid]+lred[192+tid]);
}

// ---- kFPS: grid (8, par?4:3, nb) x 512 thr. R11 rendezvous (proven).
// g==3 blocks (par only): zero non-aliased space during the rendezvous.
__global__ void __launch_bounds__(512) kFPS(const void* __restrict__ ev,
    const void* __restrict__ gWk, const void* __restrict__ gWv,
    const void* __restrict__ gWpe, const void* __restrict__ gWsa1,
    const void* __restrict__ gWsa2, float* __restrict__ ws,
    int offA, int strA, int offB, int strB, int offC, int strC,
    int offSp, int strSp, int tail, int bb0){
  const int g = blockIdx.y, idx = blockIdx.x;
  const int bb = bb0 + blockIdx.z;
  const int tid = threadIdx.x, lane = tid & 63, w = tid >> 6;

  if (g == 3){
    // par-mode only. Zero this batch's space minus the A/C-aliased prefix.
    // bb=0 space = [offSp, offSp+SPB); aliased prefix = [offSp, offSp+4NC).
    // bb=1 space = [offSp+SPB, offSp+2SPB); fully non-aliased.
    float4 z = make_float4(0.f, 0.f, 0.f, 0.f);
    size_t base; unsigned cnt4;
    if (blockIdx.z == 0){ base = (size_t)offSp + 4u*NC; cnt4 = (SPB - 4*NC)/4; }
    else                { base = (size_t)offSp + (size_t)strSp; cnt4 = SPB/4; }
    float4* p = (float4*)(ws + base);
    for (unsigned i = idx*512u + tid; i < cnt4; i += 8u*512u) p[i] = z;
    return;
  }

  const float* pts = ws + (g == 0 ? offB + (size_t)bb*strB
                         : g == 1 ? offA + (size_t)bb*strA
                                  : offC + (size_t)bb*strC);
  ull* slot = (ull*)(ws + tail + TT_SYNC + (bb*3 + g)*32);  // [par][blk] 2x8 ull
  int* gcnt = (int*)(ws + tail + TT_GCNT + bb*16);

  __shared__ float cent[64];
  __shared__ float lxsS[64];
  __shared__ ull   wvS[8];
  __shared__ int   selS[16];
  __shared__ int   sCur;
  __shared__ float gfS[1024];
  __shared__ float betaS[16];
  __shared__ float GS[64];

  const int n0 = idx*1024 + tid;       // +0 and +512
  float4 P[2][16];
#pragma unroll
  for (int j = 0; j < 2; j++)
#pragma unroll
    for (int i = 0; i < 16; i++)
      P[j][i] = ((const float4*)(pts + (size_t)(n0 + j*512)*64))[i];

  const bool bf = isbf(ev);
  // head: LXSUM accumulated by kC; cent analytically per group
  if (tid < 64){
    float lxs = ws[tail + TT_LXS + bb*64 + tid];
    lxsS[tid] = lxs;
    float c;
    if (g == 0) c = lxs * (1.0f/NB);
    else {
      const void* W = (g == 1) ? gWk : gWv;
      float s = 0.f;
#pragma unroll
      for (int j = 0; j < 64; j++) s += __shfl(lxs, j, 64) * ld(W, j*64 + tid, bf);
      c = s * (1.0f/NB);
    }
    cent[tid] = c;
  }
  __syncthreads();

  const float4* cv = (const float4*)cent;
  float md[2] = {1e10f, 1e10f};
  int cur;

  // phase 1: farthest0 (dist to bary, no md update)
  {
    float dd[2];
#pragma unroll
    for (int j = 0; j < 2; j++){
      float d = 0.f;
#pragma unroll
      for (int i = 0; i < 16; i++){
        float4 c = cv[i];
        float dx = P[j][i].x-c.x, dy = P[j][i].y-c.y, dz = P[j][i].z-c.z, dw = P[j][i].w-c.w;
        d += dx*dx; d += dy*dy; d += dz*dz; d += dw*dw;
      }
      dd[j] = d;
    }
    ull p0 = packPDI(1, dd[0], n0);
    ull p1 = packPDI(1, dd[1], n0 + 512);
    ull bp = waveMaxU64(p0 > p1 ? p0 : p1);
    if (lane == 0) wvS[w] = bp;
    __syncthreads();
    if (w == 0){
      ull v = (lane < 8) ? wvS[lane] : 0;
#pragma unroll
      for (int m = 1; m < 8; m <<= 1){
        ull o = (ull)__shfl_xor((long long)v, m, 64);
        if (o > v) v = o;
      }
      if (lane == 0)
        __hip_atomic_store(&slot[8 + idx], v, __ATOMIC_RELEASE, __HIP_MEMORY_SCOPE_AGENT);
      ull got;
      for (;;){
        got = (lane < 8) ? __hip_atomic_load(&slot[8 + lane], __ATOMIC_RELAXED, __HIP_MEMORY_SCOPE_AGENT) : 0;
        ull ok = __ballot(lane >= 8 || (int)(got >> 45) == 1);
        if (ok == ~0ull) break;
        __builtin_amdgcn_s_sleep(1);
      }
#pragma unroll
      for (int m = 1; m < 8; m <<= 1){
        ull o = (ull)__shfl_xor((long long)got, m, 64);
        if (o > got) got = o;
      }
      if (lane == 0) sCur = unpackI(got);
    }
    __syncthreads();
    cur = sCur;
  }

  for (int it = 0; ; it++){
    if (tid == 0) selS[it] = cur;
    if (it == 15) break;
    if (tid < 16) ((float4*)cent)[tid] = ((const float4*)(pts + (size_t)cur*64))[tid];
    __syncthreads();
    const int phase = it + 2;
    float dd[2];
#pragma unroll
    for (int j = 0; j < 2; j++){
      float d = 0.f;
#pragma unroll
      for (int i = 0; i < 16; i++){
        float4 c = cv[i];
        float dx = P[j][i].x-c.x, dy = P[j][i].y-c.y, dz = P[j][i].z-c.z, dw = P[j][i].w-c.w;
        d += dx*dx; d += dy*dy; d += dz*dz; d += dw*dw;
      }
      md[j] = fminf(md[j], d);
      dd[j] = md[j];
    }
    ull p0 = packPDI(phase, dd[0], n0);
    ull p1 = packPDI(phase, dd[1], n0 + 512);
    ull bp = waveMaxU64(p0 > p1 ? p0 : p1);
    if (lane == 0) wvS[w] = bp;
    __syncthreads();
    const int par = phase & 1;
    if (w == 0){
      ull v = (lane < 8) ? wvS[lane] : 0;
#pragma unroll
      for (int m = 1; m < 8; m <<= 1){
        ull o = (ull)__shfl_xor((long long)v, m, 64);
        if (o > v) v = o;
      }
      if (lane == 0)
        __hip_atomic_store(&slot[par*8 + idx], v, __ATOMIC_RELEASE, __HIP_MEMORY_SCOPE_AGENT);
      ull got;
      for (;;){
        got = (lane < 8) ? __hip_atomic_load(&slot[par*8 + lane], __ATOMIC_RELAXED, __HIP_MEMORY_SCOPE_AGENT) : 0;
        ull ok = __ballot(lane >= 8 || (int)(got >> 45) == phase);
        if (ok == ~0ull) break;
        __builtin_amdgcn_s_sleep(1);
      }
#pragma unroll
      for (int m = 1; m < 8; m <<= 1){
        ull o = (ull)__shfl_xor((long long)got, m, 64);
        if (o > got) got = o;
      }
      if (lane == 0) sCur = unpackI(got);
    }
    __syncthreads();
    cur = sCur;
  }
  __syncthreads();

  if (idx == 0){
    if (tid == 0){
      for (int i = 1; i < 16; i++){
        int key = selS[i]; int j = i - 1;
        while (j >= 0 && selS[j] > key){ selS[j+1] = selS[j]; j--; }
        selS[j+1] = key;
      }
    }
    __syncthreads();
    for (int idx2 = tid; idx2 < 1024; idx2 += 512)
      ws[tail + TT_SEL + bb*3072 + g*1024 + idx2] = pts[(size_t)selS[idx2 >> 6]*64 + (idx2 & 63)];
    __threadfence();
  }
  __syncthreads();
  if (tid == 0) atomicAdd(gcnt, 1);
  if (g != 0 || idx != 0) return;

  // ---- kG tail (per batch); wpec register-resident (P dead here)
  if (tid == 0){
    while (__hip_atomic_load(gcnt, __ATOMIC_RELAXED, __HIP_MEMORY_SCOPE_AGENT) < 24)
      __builtin_amdgcn_s_sleep(1);
    __threadfence();
  }
  __syncthreads();
  if (tid < 64){
    const float gw1 = ld(gWsa1, tid, bf);
    float wpec[64];
#pragma unroll
    for (int cn = 0; cn < 64; cn++) wpec[cn] = ld(gWpe, cn*64 + tid, bf);
    float lxs = lxsS[tid];
    float G = 0.f;
#pragma unroll
    for (int cn = 0; cn < 64; cn++) G += __shfl(lxs, cn, 64) * wpec[cn];
    GS[tid] = G;
    const float* selp = ws + tail + TT_SEL + bb*3072;
    for (int m = 0; m < 16; m++){
      float plx = selp[m*64 + tid];
      float g2 = 0.f;
#pragma unroll
      for (int cn = 0; cn < 64; cn++) g2 += __shfl(plx, cn, 64) * wpec[cn];
      gfS[m*64 + tid] = g2;
      float pkv = selp[1024 + m*64 + tid];
      float part = waveSum((pkv + g2) * gw1);
      if (tid == 0) betaS[m] = part;
    }
  }
  __syncthreads();
  if (tid < 64){
    float mx = -1e30f;
    for (int m = 0; m < 16; m++) mx = fmaxf(mx, -betaS[m]);
    float ssum = 0.f;
    for (int m = 0; m < 16; m++) ssum += expf(-betaS[m] - mx);
    float A = 0.f;
    for (int m = 0; m < 16; m++){
      float sg = expf(-betaS[m] - mx) / ssum;
      float pv = ws[tail + TT_SEL + bb*3072 + 2048 + m*64 + tid];
      float Sg = 8192.0f * (pv - gfS[m*64 + tid]) + GS[tid];
      A += sg * Sg;
    }
    float cg = 0.f;
#pragma unroll
    for (int cn = 0; cn < 64; cn++) cg += __shfl(A, cn, 64) * ld(gWsa2, cn*64 + tid, bf);
    ws[tail + TT_CG + bb*64 + tid] = cg;
  }
}

// ---- kZero: zero [base, base+count4*4) floats (float4 stores)
__global__ void kZero(float* __restrict__ ws, int base, unsigned count4){
  unsigned i = blockIdx.x*256u + threadIdx.x;
  if (i < count4)
    ((float4*)(ws + base))[i] = make_float4(0.f, 0.f, 0.f, 0.f);
}

// ---- kImg: LN + GELU + scatter-add
__global__ void __launch_bounds__(256, 4) kImg(const void* __restrict__ ev,
    const void* __restrict__ lnw, const void* __restrict__ lnb,
    float* __restrict__ ws, int offB, int strB, int offSp, int strSp,
    int tail, int bb0){
  const bool bf = isbf(ev);
  const int bb = bb0 + blockIdx.z;
  const int lane = threadIdx.x & 63, w = threadIdx.x >> 6;
  const float cg = ws[tail + TT_CG + bb*64 + lane];
  const float lw = ld(lnw, lane, bf), lb = ld(lnb, lane, bf);
  float* space = ws + offSp + (size_t)bb*strSp;
  const float* Bp = ws + offB + (size_t)bb*strB;
#pragma unroll
  for (int i = 0; i < 2; i++){
    const int n = blockIdx.x*8 + w + 4*i;
    float x = Bp[n*64 + lane] + cg;
    float mu = waveSum(x) * (1.0f/64.0f);
    float dv = x - mu;
    float var = waveSum(dv*dv) * (1.0f/64.0f);
    float xn = dv / sqrtf(var + 1e-5f);
    float y = xn * lw + lb;
    float h = 0.5f * y * (1.0f + erff(y * 0.70710678118654752f));
    const int e4 = (bb*NB + n)*4;
    float exf = ld(ev, e4+0, bf), eyf = ld(ev, e4+1, bf), epf = ld(ev, e4+3, bf);
    int xi = (int)floorf(exf), yi = (int)floorf(eyf);
    int flat = yi*IMG_W + xi;
    flat = max(0, min(HWPIX-1, flat));
    atomicAdd(space + flat*64 + lane, epf * h);
  }
}

// ---- kStat: cnt,sum,sumsq per batch
__global__ void __launch_bounds__(256) kStat(float* __restrict__ ws,
    int offSp, int strSp, int tail, int bb0){
  const int bb = bb0 + blockIdx.z;
  const float4* sp = (const float4*)(ws + offSp + (size_t)bb*strSp);
  float cnt = 0.f, sum = 0.f, ssq = 0.f;
  for (unsigned i = blockIdx.x*256u + threadIdx.x; i < SPB/4; i += 65536u){
    float4 v = sp[i];
    if (v.x != 0.f){ cnt += 1.f; sum += v.x; ssq += v.x*v.x; }
    if (v.y != 0.f){ cnt += 1.f; sum += v.y; ssq += v.y*v.y; }
    if (v.z != 0.f){ cnt += 1.f; sum += v.z; ssq += v.z*v.z; }
    if (v.w != 0.f){ cnt += 1.f; sum += v.w; ssq += v.w*v.w; }
  }
  cnt = waveSum(cnt); sum = waveSum(sum); ssq = waveSum(ssq);
  __shared__ float rc[4], rs[4], rq[4];
  const int lane = threadIdx.x & 63, w = threadIdx.x >> 6;
  if (lane == 0){ rc[w] = cnt; rs[w] = sum; rq[w] = ssq; }
  __syncthreads();
  if (threadIdx.x == 0){
    atomicAdd(&ws[tail + TT_STATS + bb*16 + 0], rc[0]+rc[1]+rc[2]+rc[3]);
    atomicAdd(&ws[tail + TT_STATS + bb*16 + 1], rs[0]+rs[1]+rs[2]+rs[3]);
    atomicAdd(&ws[tail + TT_STATS + bb*16 + 2], rq[0]+rq[1]+rq[2]+rq[3]);
  }
}

// ---- kOut: LDS-transpose 64hw x 64c (stride 65: 2-way banks = free);
// var from sum/sumsq
__global__ void __launch_bounds__(256) kOut(const void* __restrict__ ev,
    const float* __restrict__ ws, void* __restrict__ out,
    int offSp, int strSp, int tail, int bb0){
  const bool bf = isbf(ev);
  const int bb = bb0 + blockIdx.z;
  __shared__ float tile[64*65];
  const int tid = threadIdx.x;
  const int hw0 = blockIdx.x*64;
  const float* sp = ws + offSp + (size_t)bb*strSp;
#pragma unroll
  for (int i = 0; i < 16; i++){
    int idx = tid + 256*i;
    tile[(idx >> 6)*65 + (idx & 63)] = sp[(size_t)hw0*64 + idx];
  }
  const float cnt = ws[tail + TT_STATS + bb*16 + 0];
  const float sum = ws[tail + TT_STATS + bb*16 + 1];
  const float ssq = ws[tail + TT_STATS + bb*16 + 2];
  const float mean = sum / fmaxf(cnt, 1.f);
  const float m2   = fmaxf(ssq - sum*mean, 0.f);
  const float var  = m2 / fmaxf(cnt - 1.f, 1.f);
  const float stdv = sqrtf(var);
  __syncthreads();
  const int c = tid >> 2, sub = tid & 3;
#pragma unroll
  for (int j = 0; j < 16; j++){
    int hwl = sub*16 + j;
    float x = tile[hwl*65 + c];
    float centered = (x != 0.f) ? (x - mean) : x;
    float normed = (stdv > 0.f) ? (centered / stdv) : centered;
    float o = (cnt > 0.f) ? normed : x;
    stout(out, (long)(bb*64 + c)*HWPIX + hw0 + hwl, o, bf);
  }
}

extern "C" void kernel_launch(void* const* d_in, const int* in_sizes, int n_in,
                              void* d_out, int out_size, void* d_ws, size_t ws_size,
                              hipStream_t stream){
  (void)in_sizes; (void)n_in; (void)out_size;
  const void* ev     = d_in[0];
  const void* Wm     = d_in[1];
  const void* Wpe    = d_in[2];
  const void* lnw    = d_in[3];
  const void* lnb    = d_in[4];
  const void* lxWq   = d_in[5];
  const void* lxWk   = d_in[6];
  const void* lxWv   = d_in[7];
  const void* lxWsa1 = d_in[8];
  const void* lxWsa2 = d_in[9];
  // d_in[10] = gx_Wq : unused (cancels in n-independent softmax)
  const void* gxWk   = d_in[11];
  const void* gxWv   = d_in[12];
  const void* gxWpe  = d_in[13];
  const void* gxWsa1 = d_in[14];
  const void* gxWsa2 = d_in[15];
  float* ws = (float*)d_ws;

  // Parallel layout: B[2NC] | SPACE[2SPB] (aliases A,C) | tail
  const int P_TAIL = 2*NC + 2*SPB;
  const size_t PAR_BYTES = (size_t)(P_TAIL + TT_TOT) * 4;
  const bool par = ws_size >= PAR_BYTES;

  int offB, strB, offSp, strSp, offA, strA, offC, strC, tail;
  if (par){
    offB = 0;        strB = NC;
    offSp = 2*NC;    strSp = SPB;
    offA = 2*NC;     strA = NC;
    offC = 4*NC;     strC = NC;
    tail = P_TAIL;
  } else {
    offSp = 0;       strSp = 0;
    offA = 0;        strA = 0;
    offC = NC;       strC = 0;
    offB = SPB;      strB = 0;
    tail = SPB + NC;
  }
  const int nb = par ? 2 : 1;
  const int iters = par ? 1 : 2;

  kW<<<1, 256, 0, stream>>>(ev, lxWq, lxWk, Wpe, lxWsa1, ws, tail);
  for (int t = 0; t < iters; t++){
    const int bb0 = par ? 0 : t;
    kA<<<dim3(1024,1,nb), 256, 0, stream>>>(ev, Wm, Wpe, lxWv, ws, offA, strA, tail, bb0);
    kB<<<dim3(16,1,nb), 64, 0, stream>>>(ev, Wm, lxWv, lxWsa2, ws, tail, bb0);
    kC<<<dim3(1024,1,nb), 256, 0, stream>>>(ev, gxWk, gxWv, ws,
        offA, strA, offB, strB, offC, strC, tail, bb0);
    kFPS<<<dim3(8, par ? 4 : 3, nb), 512, 0, stream>>>(ev, gxWk, gxWv, gxWpe, gxWsa1, gxWsa2, ws,
        offA, strA, offB, strB, offC, strC, offSp, strSp, tail, bb0);
    if (par)
      kZero<<<dim3(2048,1,1), 256, 0, stream>>>(ws, offSp, (unsigned)NC);        // 8MB aliased prefix
    else
      kZero<<<dim3(2700,1,1), 256, 0, stream>>>(ws, offSp, (unsigned)(SPB/4));   // full space
    kImg<<<dim3(1024,1,nb), 256, 0, stream>>>(ev, lnw, lnb, ws, offB, strB, offSp, strSp, tail, bb0);
    kStat<<<dim3(256,1,nb), 256, 0, stream>>>(ws, offSp, strSp, tail, bb0);
    kOut<<<dim3(675,1,nb), 256, 0, stream>>>(ev, ws, d_out, offSp, strSp, tail, bb0);
  }
}